// Round 1
// baseline (29088.400 us; speedup 1.0000x reference)
//
#include <hip/hip_runtime.h>

typedef unsigned short u16;
typedef unsigned int u32;
typedef __bf16 bf16x8 __attribute__((ext_vector_type(8)));
typedef float f32x4 __attribute__((ext_vector_type(4)));

#define T_LEN 512
#define BATCH 64
#define FIN 128
#define UNITS 1024

// ---- workspace layout (bytes) ----
#define O_BAR   0
#define O_XBF   4096
#define SZ_XBF  (T_LEN*BATCH*FIN*2)
#define O_WP0   (O_XBF + SZ_XBF)
#define SZ_WP0  (1152*4096*2)
#define O_WP1   (O_WP0 + SZ_WP0)
#define SZ_WP1  (2048*4096*2)
#define O_WFC   (O_WP1 + SZ_WP1)
#define SZ_WFC  (16*1024*2)
#define O_H0    (O_WFC + SZ_WFC)
#define SZ_H    (2*BATCH*UNITS*2)
#define O_H1    (O_H0 + SZ_H)
#define WS_NEED (O_H1 + SZ_H)

__device__ __forceinline__ float bf2f(u16 s) {
  u32 u = ((u32)s) << 16;
  return __builtin_bit_cast(float, u);
}
__device__ __forceinline__ u16 f2bf(float f) {
  u32 u = __builtin_bit_cast(u32, f);
  u32 r = (u + 0x7FFFu + ((u >> 16) & 1u)) >> 16;
  return (u16)r;
}
__device__ __forceinline__ float sigm(float x) { return 1.0f / (1.0f + __expf(-x)); }
__device__ __forceinline__ float tanhft(float x) { return 1.0f - 2.0f / (__expf(2.0f * x) + 1.0f); }

// ---------------- prep kernels ----------------
__global__ void k_zero(u32* p, int n) {
  int i = blockIdx.x * 256 + threadIdx.x;
  if (i < n) p[i] = 0u;
}

// xbf[t][b][f] = inputs[b][t][f]
__global__ void k_pack_x(const float* __restrict__ src, u16* __restrict__ dst) {
  int i = blockIdx.x * 256 + threadIdx.x;      // < 512*64*128
  int f = i & 127, tb = i >> 7;
  int b = tb & 63, t = tb >> 6;
  dst[i] = f2bf(src[(b * T_LEN + t) * FIN + f]);
}

// Wp0: [ug][nt][ktg(36)][lane][8] over K=[W0(128);U0(1024)], cols permuted unit-gate interleaved
__global__ void k_pack_w0(const float* __restrict__ W0, const float* __restrict__ U0,
                          u16* __restrict__ dst) {
  int i = blockIdx.x * 256 + threadIdx.x;      // < 4096*1152
  int j = i & 7, lane = (i >> 3) & 63, rest = i >> 9;
  int ktg = rest % 36, tmp = rest / 36;
  int nt = tmp & 3, ug = tmp >> 2;
  int k = ktg * 32 + ((lane >> 4) << 3) + j;
  int rr = nt * 16 + (lane & 15);
  int gate = rr & 3, ul = rr >> 2;
  int col = gate * 1024 + ug * 16 + ul;
  float v = (k < FIN) ? W0[k * 4096 + col] : U0[(k - FIN) * 4096 + col];
  dst[i] = f2bf(v);
}

// Wp1: [ug][nt][ktg(64)][lane][8] over K=[W1(1024);U1(1024)]
__global__ void k_pack_w1(const float* __restrict__ W1, const float* __restrict__ U1,
                          u16* __restrict__ dst) {
  int i = blockIdx.x * 256 + threadIdx.x;      // < 4096*2048
  int j = i & 7, lane = (i >> 3) & 63, rest = i >> 9;
  int ktg = rest & 63, tmp = rest >> 6;
  int nt = tmp & 3, ug = tmp >> 2;
  int k = ktg * 32 + ((lane >> 4) << 3) + j;
  int rr = nt * 16 + (lane & 15);
  int gate = rr & 3, ul = rr >> 2;
  int col = gate * 1024 + ug * 16 + ul;
  float v = (k < UNITS) ? W1[k * 4096 + col] : U1[(k - UNITS) * 4096 + col];
  dst[i] = f2bf(v);
}

// WfcT[c][k] = Wfc[k][c]
__global__ void k_pack_wfc(const float* __restrict__ Wfc, u16* __restrict__ dst) {
  int i = blockIdx.x * 256 + threadIdx.x;      // < 16*1024
  int k = i & 1023, c = i >> 10;
  dst[c * 1024 + k] = f2bf(Wfc[k * 16 + c]);
}

// ---------------- persistent kernel ----------------
struct KP {
  const u16* xbf; const u16* wp0; const u16* wp1; const u16* wfc;
  u16* h0; u16* h1; u32* bar;
  const float* b0; const float* g0; const float* be0;
  const float* b1; const float* g1; const float* be1;
  const float* bfc; float* out;
};

__device__ __forceinline__ void bg_barrier(u32* ctr, u32* gen) {
  __syncthreads();
  if (threadIdx.x == 0) {
    u32 g = __hip_atomic_load(gen, __ATOMIC_RELAXED, __HIP_MEMORY_SCOPE_AGENT);
    u32 old = __hip_atomic_fetch_add(ctr, 1u, __ATOMIC_ACQ_REL, __HIP_MEMORY_SCOPE_AGENT);
    if (old == 63u) {
      __hip_atomic_store(ctr, 0u, __ATOMIC_RELAXED, __HIP_MEMORY_SCOPE_AGENT);
      __hip_atomic_store(gen, g + 1u, __ATOMIC_RELEASE, __HIP_MEMORY_SCOPE_AGENT);
    } else {
      while (__hip_atomic_load(gen, __ATOMIC_ACQUIRE, __HIP_MEMORY_SCOPE_AGENT) == g) {
        __builtin_amdgcn_s_sleep(2);
      }
    }
  }
  __syncthreads();
}

__device__ __forceinline__ void accst(uint4 v, float& s1, float& s2) {
  u32 a[4] = {v.x, v.y, v.z, v.w};
#pragma unroll
  for (int e = 0; e < 4; ++e) {
    float f0 = bf2f((u16)(a[e] & 0xffffu));
    float f1 = bf2f((u16)(a[e] >> 16));
    s1 += f0 + f1;
    s2 += f0 * f0 + f1 * f1;
  }
}

__device__ __forceinline__ uint4 normpack(uint4 v, float mu, float rs,
                                          const float* gg, const float* bb) {
  u32 a[4] = {v.x, v.y, v.z, v.w};
  u32 o[4];
#pragma unroll
  for (int e = 0; e < 4; ++e) {
    float f0 = (bf2f((u16)(a[e] & 0xffffu)) - mu) * rs * gg[2 * e] + bb[2 * e];
    float f1 = (bf2f((u16)(a[e] >> 16)) - mu) * rs * gg[2 * e + 1] + bb[2 * e + 1];
    o[e] = (u32)f2bf(f0) | ((u32)f2bf(f1) << 16);
  }
  uint4 r; r.x = o[0]; r.y = o[1]; r.z = o[2]; r.w = o[3];
  return r;
}

__global__ void __launch_bounds__(512) k_persist(KP p) {
  const int tid = threadIdx.x;
  const int ug = blockIdx.x & 63, bg = blockIdx.x >> 6;
  const int lane = tid & 63, wv = tid >> 6;
  const int nt = wv & 3, kh = wv >> 2;

  __shared__ u16 Ast[16][1160];                 // A staging (padded: +8 breaks bank aliasing)
  __shared__ float zb[2][16][68];               // kh-partial z tiles
  __shared__ float g0s[1024], be0s[1024], g1s[1024], be1s[1024];
  __shared__ float b0s[64], b1s[64];
  __shared__ float mu_s[16], sg_s[16];
  __shared__ float red[8][2];
  __shared__ float lbuf[16];

  for (int i = tid; i < 1024; i += 512) {
    g0s[i] = p.g0[i]; be0s[i] = p.be0[i];
    g1s[i] = p.g1[i]; be1s[i] = p.be1[i];
  }
  if (tid < 64) {
    int gate = tid & 3, ul = tid >> 2;
    b0s[tid] = p.b0[gate * 1024 + ug * 16 + ul];
    b1s[tid] = p.b1[gate * 1024 + ug * 16 + ul];
  }

  // resident weight fragments (bf16, MFMA B-operand order)
  bf16x8 w0r[18], w1r[32];
  {
    const u16* q0 = p.wp0 + (size_t)(((ug * 4 + nt) * 36 + kh * 18) * 64 + lane) * 8;
#pragma unroll
    for (int s = 0; s < 18; ++s)
      w0r[s] = __builtin_bit_cast(bf16x8, *(const uint4*)(q0 + (size_t)s * 512));
    const u16* q1 = p.wp1 + (size_t)(((ug * 4 + nt) * 64 + kh * 32) * 64 + lane) * 8;
#pragma unroll
    for (int s = 0; s < 32; ++s)
      w1r[s] = __builtin_bit_cast(bf16x8, *(const uint4*)(q1 + (size_t)s * 512));
  }

  u32* ctr = p.bar + bg * 32;
  u32* gen = p.bar + 512 + bg * 32;

  float c0 = 0.f, c1 = 0.f;                     // cell state, tid<256: (row=tid>>4, unit=tid&15)
  const int gr = tid >> 4, gu = tid & 15;
  const int srow = tid >> 5, ssub = tid & 31;   // staging map
  const int am = lane & 15, aq = (lane >> 4) << 3;  // A-frag: row=lane&15, k+= (lane>>4)*8

  __syncthreads();

  for (int t = 0; t < T_LEN; ++t) {
    const int cur = t & 1, rd = cur ^ 1;

    // ======== L0: stage A = [x_t | h0(t-1)] ========
    {
      const u16* xr = p.xbf + (size_t)(t * 64 + bg * 16 + srow) * FIN + ssub * 4;
      uint2 xv = *(const uint2*)xr;
      const u16* hr = p.h0 + (size_t)(rd * 64 + bg * 16 + srow) * UNITS + ssub * 8;
      uint4 h0v = *(const uint4*)(hr);
      uint4 h1v = *(const uint4*)(hr + 256);
      uint4 h2v = *(const uint4*)(hr + 512);
      uint4 h3v = *(const uint4*)(hr + 768);
      *(uint2*)&Ast[srow][ssub * 4] = xv;
      *(uint4*)&Ast[srow][128 + ssub * 8] = h0v;
      *(uint4*)&Ast[srow][128 + 256 + ssub * 8] = h1v;
      *(uint4*)&Ast[srow][128 + 512 + ssub * 8] = h2v;
      *(uint4*)&Ast[srow][128 + 768 + ssub * 8] = h3v;
    }
    __syncthreads();

    // ======== L0 MFMA: z0 (wave = nt cols, kh K-half) ========
    f32x4 acc0 = {0.f, 0.f, 0.f, 0.f};
    {
      const int kb = kh * 576;
#pragma unroll
      for (int s = 0; s < 18; ++s) {
        bf16x8 a = __builtin_bit_cast(bf16x8, *(const uint4*)&Ast[am][kb + s * 32 + aq]);
        acc0 = __builtin_amdgcn_mfma_f32_16x16x32_bf16(a, w0r[s], acc0, 0, 0, 0);
      }
    }
#pragma unroll
    for (int i = 0; i < 4; ++i)
      zb[kh][(lane >> 4) * 4 + i][nt * 16 + (lane & 15)] = acc0[i];
    __syncthreads();

    // ======== gates layer0 ========
    if (tid < 256) {
      const float* zr0 = &zb[0][gr][gu * 4];
      const float* zr1 = &zb[1][gr][gu * 4];
      float zi = zr0[0] + zr1[0] + b0s[gu * 4 + 0];
      float zf = zr0[1] + zr1[1] + b0s[gu * 4 + 1];
      float zg = zr0[2] + zr1[2] + b0s[gu * 4 + 2];
      float zo = zr0[3] + zr1[3] + b0s[gu * 4 + 3];
      float gi = sigm(zi), gf = sigm(zf), gg = tanhft(zg), go = sigm(zo);
      c0 = gf * c0 + gi * gg;
      float h = go * tanhft(c0);
      p.h0[(size_t)(cur * 64 + bg * 16 + gr) * UNITS + ug * 16 + gu] = f2bf(h);
    }
    bg_barrier(ctr, gen);  // ---- A: h0(t) visible within batch-group ----

    // ======== stats(h0) -> stage o0 ; then h1 ; L1 MFMA ========
    f32x4 acc1 = {0.f, 0.f, 0.f, 0.f};
    {
      const u16* h0r = p.h0 + (size_t)(cur * 64 + bg * 16 + srow) * UNITS + ssub * 8;
      uint4 a0 = *(const uint4*)(h0r);
      uint4 a1 = *(const uint4*)(h0r + 256);
      uint4 a2 = *(const uint4*)(h0r + 512);
      uint4 a3 = *(const uint4*)(h0r + 768);
      const u16* h1r = p.h1 + (size_t)(rd * 64 + bg * 16 + srow) * UNITS + ssub * 8;
      uint4 b0v = *(const uint4*)(h1r);
      uint4 b1v = *(const uint4*)(h1r + 256);
      uint4 b2v = *(const uint4*)(h1r + 512);
      uint4 b3v = *(const uint4*)(h1r + 768);

      float s1 = 0.f, s2 = 0.f;
      accst(a0, s1, s2); accst(a1, s1, s2); accst(a2, s1, s2); accst(a3, s1, s2);
#pragma unroll
      for (int m = 1; m <= 16; m <<= 1) { s1 += __shfl_xor(s1, m); s2 += __shfl_xor(s2, m); }
      if (ssub == 0) {
        float mu = s1 * (1.0f / 1024.0f);
        float va = s2 * (1.0f / 1024.0f) - mu * mu;
        mu_s[srow] = mu;
        sg_s[srow] = rsqrtf(va + 1e-3f);
      }
      __syncthreads();
      float mu = mu_s[srow], rs = sg_s[srow];
      *(uint4*)&Ast[srow][ssub * 8]       = normpack(a0, mu, rs, &g0s[ssub * 8], &be0s[ssub * 8]);
      *(uint4*)&Ast[srow][256 + ssub * 8] = normpack(a1, mu, rs, &g0s[256 + ssub * 8], &be0s[256 + ssub * 8]);
      *(uint4*)&Ast[srow][512 + ssub * 8] = normpack(a2, mu, rs, &g0s[512 + ssub * 8], &be0s[512 + ssub * 8]);
      *(uint4*)&Ast[srow][768 + ssub * 8] = normpack(a3, mu, rs, &g0s[768 + ssub * 8], &be0s[768 + ssub * 8]);
      __syncthreads();
      if (kh == 0) {
#pragma unroll
        for (int s = 0; s < 32; ++s) {
          bf16x8 a = __builtin_bit_cast(bf16x8, *(const uint4*)&Ast[am][s * 32 + aq]);
          acc1 = __builtin_amdgcn_mfma_f32_16x16x32_bf16(a, w1r[s], acc1, 0, 0, 0);
        }
      }
      __syncthreads();
      *(uint4*)&Ast[srow][ssub * 8]       = b0v;
      *(uint4*)&Ast[srow][256 + ssub * 8] = b1v;
      *(uint4*)&Ast[srow][512 + ssub * 8] = b2v;
      *(uint4*)&Ast[srow][768 + ssub * 8] = b3v;
      __syncthreads();
      if (kh == 1) {
#pragma unroll
        for (int s = 0; s < 32; ++s) {
          bf16x8 a = __builtin_bit_cast(bf16x8, *(const uint4*)&Ast[am][s * 32 + aq]);
          acc1 = __builtin_amdgcn_mfma_f32_16x16x32_bf16(a, w1r[s], acc1, 0, 0, 0);
        }
      }
    }
#pragma unroll
    for (int i = 0; i < 4; ++i)
      zb[kh][(lane >> 4) * 4 + i][nt * 16 + (lane & 15)] = acc1[i];
    __syncthreads();

    // ======== gates layer1 ========
    if (tid < 256) {
      const float* zr0 = &zb[0][gr][gu * 4];
      const float* zr1 = &zb[1][gr][gu * 4];
      float zi = zr0[0] + zr1[0] + b1s[gu * 4 + 0];
      float zf = zr0[1] + zr1[1] + b1s[gu * 4 + 1];
      float zg = zr0[2] + zr1[2] + b1s[gu * 4 + 2];
      float zo = zr0[3] + zr1[3] + b1s[gu * 4 + 3];
      float gi = sigm(zi), gf = sigm(zf), gg = tanhft(zg), go = sigm(zo);
      c1 = gf * c1 + gi * gg;
      float h = go * tanhft(c1);
      p.h1[(size_t)(cur * 64 + bg * 16 + gr) * UNITS + ug * 16 + gu] = f2bf(h);
    }
    bg_barrier(ctr, gen);  // ---- B: h1(t) visible ----

    // ======== FC + softmax (one block per batch row) ========
    if (ug < 16) {
      const int row = bg * 16 + ug;
      const u16* hr = p.h1 + (size_t)(cur * 64 + row) * UNITS;
      u32 hv = *(const u32*)(hr + tid * 2);
      float f0 = bf2f((u16)(hv & 0xffffu)), f1 = bf2f((u16)(hv >> 16));
      float s1 = f0 + f1, s2 = f0 * f0 + f1 * f1;
#pragma unroll
      for (int m = 1; m <= 32; m <<= 1) { s1 += __shfl_xor(s1, m); s2 += __shfl_xor(s2, m); }
      if (lane == 0) { red[wv][0] = s1; red[wv][1] = s2; }
      __syncthreads();
      if (tid == 0) {
        float t1 = 0.f, t2 = 0.f;
#pragma unroll
        for (int w2 = 0; w2 < 8; ++w2) { t1 += red[w2][0]; t2 += red[w2][1]; }
        float mu = t1 * (1.0f / 1024.0f);
        float va = t2 * (1.0f / 1024.0f) - mu * mu;
        mu_s[0] = mu;
        sg_s[0] = rsqrtf(va + 1e-3f);
      }
      __syncthreads();
      {
        float mu = mu_s[0], rs = sg_s[0];
        float* o1f = (float*)&Ast[0][0];
        o1f[tid * 2]     = (f0 - mu) * rs * g1s[tid * 2]     + be1s[tid * 2];
        o1f[tid * 2 + 1] = (f1 - mu) * rs * g1s[tid * 2 + 1] + be1s[tid * 2 + 1];
      }
      __syncthreads();
      if (tid < 256) {
        const int cls = tid & 15, ks = tid >> 4;
        const float* o1f = (const float*)&Ast[0][0];
        const u16* wrow = p.wfc + cls * 1024 + ks * 64;
        float pa = 0.f;
#pragma unroll
        for (int q8 = 0; q8 < 8; ++q8) {
          uint4 wv4 = *(const uint4*)(wrow + q8 * 8);
          u32 aa[4] = {wv4.x, wv4.y, wv4.z, wv4.w};
#pragma unroll
          for (int e = 0; e < 4; ++e) {
            int k = ks * 64 + q8 * 8 + e * 2;
            pa += o1f[k]     * bf2f((u16)(aa[e] & 0xffffu));
            pa += o1f[k + 1] * bf2f((u16)(aa[e] >> 16));
          }
        }
        zb[0][ks][cls] = pa;
      }
      __syncthreads();
      if (tid < 16) {
        float lg = p.bfc[tid];
#pragma unroll
        for (int ks = 0; ks < 16; ++ks) lg += zb[0][ks][tid];
        lbuf[tid] = lg;
      }
      __syncthreads();
      if (tid < 16) {
        float mx = lbuf[0];
#pragma unroll
        for (int j2 = 1; j2 < 16; ++j2) mx = fmaxf(mx, lbuf[j2]);
        float ssum = 0.f;
#pragma unroll
        for (int j2 = 0; j2 < 16; ++j2) ssum += __expf(lbuf[j2] - mx);
        p.out[((size_t)row * T_LEN + t) * 16 + tid] = __expf(lbuf[tid] - mx) / ssum;
      }
    }
  }
}

extern "C" void kernel_launch(void* const* d_in, const int* in_sizes, int n_in,
                              void* d_out, int out_size, void* d_ws, size_t ws_size,
                              hipStream_t stream) {
  (void)in_sizes; (void)n_in; (void)out_size;
  if (ws_size < (size_t)WS_NEED) return;

  const float* inp = (const float*)d_in[0];
  const float* W0  = (const float*)d_in[1];
  const float* U0  = (const float*)d_in[2];
  const float* b0  = (const float*)d_in[3];
  const float* g0  = (const float*)d_in[4];
  const float* be0 = (const float*)d_in[5];
  const float* W1  = (const float*)d_in[6];
  const float* U1  = (const float*)d_in[7];
  const float* b1  = (const float*)d_in[8];
  const float* g1  = (const float*)d_in[9];
  const float* be1 = (const float*)d_in[10];
  const float* Wfc = (const float*)d_in[11];
  const float* bfc = (const float*)d_in[12];

  char* ws = (char*)d_ws;
  u32* bar  = (u32*)(ws + O_BAR);
  u16* xbf  = (u16*)(ws + O_XBF);
  u16* wp0  = (u16*)(ws + O_WP0);
  u16* wp1  = (u16*)(ws + O_WP1);
  u16* wfcT = (u16*)(ws + O_WFC);
  u16* h0   = (u16*)(ws + O_H0);
  u16* h1   = (u16*)(ws + O_H1);

  k_zero<<<4, 256, 0, stream>>>(bar, 1024);
  k_zero<<<512, 256, 0, stream>>>((u32*)(ws + O_H0), 131072);  // h0+h1 (contiguous)
  k_pack_x<<<16384, 256, 0, stream>>>(inp, xbf);
  k_pack_w0<<<18432, 256, 0, stream>>>(W0, U0, wp0);
  k_pack_w1<<<32768, 256, 0, stream>>>(W1, U1, wp1);
  k_pack_wfc<<<64, 256, 0, stream>>>(Wfc, wfcT);

  KP p;
  p.xbf = xbf; p.wp0 = wp0; p.wp1 = wp1; p.wfc = wfcT;
  p.h0 = h0; p.h1 = h1; p.bar = bar;
  p.b0 = b0; p.g0 = g0; p.be0 = be0;
  p.b1 = b1; p.g1 = g1; p.be1 = be1;
  p.bfc = bfc; p.out = (float*)d_out;

  void* args[] = { &p };
  hipLaunchCooperativeKernel((const void*)k_persist, dim3(256), dim3(512), args, 0, stream);
}

// Round 2
// 29027.695 us; speedup vs baseline: 1.0021x; 1.0021x over previous
//
#include <hip/hip_runtime.h>

typedef unsigned short u16;
typedef unsigned int u32;
typedef __bf16 bf16x8 __attribute__((ext_vector_type(8)));
typedef float f32x4 __attribute__((ext_vector_type(4)));

#define T_LEN 512
#define BATCH 64
#define FIN 128
#define UNITS 1024

// ---- workspace layout (bytes) ----
#define O_BAR   0
#define O_XBF   4096
#define SZ_XBF  (T_LEN*BATCH*FIN*2)
#define O_WP0   (O_XBF + SZ_XBF)
#define SZ_WP0  (1152*4096*2)
#define O_WP1   (O_WP0 + SZ_WP0)
#define SZ_WP1  (2048*4096*2)
#define O_WFC   (O_WP1 + SZ_WP1)
#define SZ_WFC  (16*1024*2)
#define O_H0    (O_WFC + SZ_WFC)
#define SZ_H    (2*BATCH*UNITS*2)
#define O_H1    (O_H0 + SZ_H)
#define WS_NEED (O_H1 + SZ_H)

__device__ __forceinline__ float bf2f(u16 s) {
  u32 u = ((u32)s) << 16;
  return __builtin_bit_cast(float, u);
}
__device__ __forceinline__ u16 f2bf(float f) {
  u32 u = __builtin_bit_cast(u32, f);
  u32 r = (u + 0x7FFFu + ((u >> 16) & 1u)) >> 16;
  return (u16)r;
}
__device__ __forceinline__ float sigm(float x) { return 1.0f / (1.0f + __expf(-x)); }
__device__ __forceinline__ float tanhft(float x) { return 1.0f - 2.0f / (__expf(2.0f * x) + 1.0f); }

// ---------------- prep kernels ----------------
__global__ void k_zero(u32* p, int n) {
  int i = blockIdx.x * 256 + threadIdx.x;
  if (i < n) p[i] = 0u;
}

// xbf[t][b][f] = inputs[b][t][f]
__global__ void k_pack_x(const float* __restrict__ src, u16* __restrict__ dst) {
  int i = blockIdx.x * 256 + threadIdx.x;      // < 512*64*128
  int f = i & 127, tb = i >> 7;
  int b = tb & 63, t = tb >> 6;
  dst[i] = f2bf(src[(b * T_LEN + t) * FIN + f]);
}

// Wp0: [ug][nt][ktg(36)][lane][8] over K=[W0(128);U0(1024)], cols unit-gate interleaved
__global__ void k_pack_w0(const float* __restrict__ W0, const float* __restrict__ U0,
                          u16* __restrict__ dst) {
  int i = blockIdx.x * 256 + threadIdx.x;      // < 4096*1152
  int j = i & 7, lane = (i >> 3) & 63, rest = i >> 9;
  int ktg = rest % 36, tmp = rest / 36;
  int nt = tmp & 3, ug = tmp >> 2;
  int k = ktg * 32 + ((lane >> 4) << 3) + j;
  int rr = nt * 16 + (lane & 15);
  int gate = rr & 3, ul = rr >> 2;
  int col = gate * 1024 + ug * 16 + ul;
  float v = (k < FIN) ? W0[k * 4096 + col] : U0[(k - FIN) * 4096 + col];
  dst[i] = f2bf(v);
}

// Wp1: [ug][nt][ktg(64)][lane][8] over K=[W1(1024);U1(1024)]
__global__ void k_pack_w1(const float* __restrict__ W1, const float* __restrict__ U1,
                          u16* __restrict__ dst) {
  int i = blockIdx.x * 256 + threadIdx.x;      // < 4096*2048
  int j = i & 7, lane = (i >> 3) & 63, rest = i >> 9;
  int ktg = rest & 63, tmp = rest >> 6;
  int nt = tmp & 3, ug = tmp >> 2;
  int k = ktg * 32 + ((lane >> 4) << 3) + j;
  int rr = nt * 16 + (lane & 15);
  int gate = rr & 3, ul = rr >> 2;
  int col = gate * 1024 + ug * 16 + ul;
  float v = (k < UNITS) ? W1[k * 4096 + col] : U1[(k - UNITS) * 4096 + col];
  dst[i] = f2bf(v);
}

// WfcT[c][k] = Wfc[k][c]
__global__ void k_pack_wfc(const float* __restrict__ Wfc, u16* __restrict__ dst) {
  int i = blockIdx.x * 256 + threadIdx.x;      // < 16*1024
  int k = i & 1023, c = i >> 10;
  dst[c * 1024 + k] = f2bf(Wfc[k * 16 + c]);
}

// ---------------- persistent kernel ----------------
struct KP {
  const u16* xbf; const u16* wp0; const u16* wp1; const u16* wfc;
  u16* h0; u16* h1; u32* bar;
  const float* b0; const float* g0; const float* be0;
  const float* b1; const float* g1; const float* be1;
  const float* bfc; float* out;
};

__device__ __forceinline__ void bg_barrier(u32* ctr, u32* gen) {
  __syncthreads();
  if (threadIdx.x == 0) {
    u32 g = __hip_atomic_load(gen, __ATOMIC_RELAXED, __HIP_MEMORY_SCOPE_AGENT);
    u32 old = __hip_atomic_fetch_add(ctr, 1u, __ATOMIC_ACQ_REL, __HIP_MEMORY_SCOPE_AGENT);
    if (old == 63u) {
      __hip_atomic_store(ctr, 0u, __ATOMIC_RELAXED, __HIP_MEMORY_SCOPE_AGENT);
      __hip_atomic_store(gen, g + 1u, __ATOMIC_RELEASE, __HIP_MEMORY_SCOPE_AGENT);
    } else {
      while (__hip_atomic_load(gen, __ATOMIC_ACQUIRE, __HIP_MEMORY_SCOPE_AGENT) == g) {
        __builtin_amdgcn_s_sleep(2);
      }
    }
  }
  __syncthreads();
}

__device__ __forceinline__ void accst(uint4 v, float& s1, float& s2) {
  u32 a[4] = {v.x, v.y, v.z, v.w};
#pragma unroll
  for (int e = 0; e < 4; ++e) {
    float f0 = bf2f((u16)(a[e] & 0xffffu));
    float f1 = bf2f((u16)(a[e] >> 16));
    s1 += f0 + f1;
    s2 += f0 * f0 + f1 * f1;
  }
}

__device__ __forceinline__ uint4 normpack(uint4 v, float mu, float rs,
                                          const float* gg, const float* bb) {
  u32 a[4] = {v.x, v.y, v.z, v.w};
  u32 o[4];
#pragma unroll
  for (int e = 0; e < 4; ++e) {
    float f0 = (bf2f((u16)(a[e] & 0xffffu)) - mu) * rs * gg[2 * e] + bb[2 * e];
    float f1 = (bf2f((u16)(a[e] >> 16)) - mu) * rs * gg[2 * e + 1] + bb[2 * e + 1];
    o[e] = (u32)f2bf(f0) | ((u32)f2bf(f1) << 16);
  }
  uint4 r; r.x = o[0]; r.y = o[1]; r.z = o[2]; r.w = o[3];
  return r;
}

__global__ void __launch_bounds__(512, 2) k_persist(KP p) {
  const int tid = threadIdx.x;
  const int ug = blockIdx.x & 63, bg = blockIdx.x >> 6;
  const int lane = tid & 63, wv = tid >> 6;
  const int nt = wv & 3, kh = wv >> 2;

  // buf0: h0(t-1) staging, then o0 staging, then FC float scratch (aliased)
  __shared__ __align__(16) u16 buf0[16][1032];
  __shared__ float zb[2][16][68];               // kh-partial z tiles
  __shared__ float g0s[1024], be0s[1024];
  __shared__ float b0s[64], b1s[64];
  __shared__ float mu_s[16], sg_s[16];
  __shared__ float red[8][2];
  __shared__ float lbuf[16];

  for (int i = tid; i < 1024; i += 512) { g0s[i] = p.g0[i]; be0s[i] = p.be0[i]; }
  if (tid < 64) {
    int gate = tid & 3, ul = tid >> 2;
    b0s[tid] = p.b0[gate * 1024 + ug * 16 + ul];
    b1s[tid] = p.b1[gate * 1024 + ug * 16 + ul];
  }
  // FC LayerNorm params as per-thread registers (indices fixed per thread)
  const float g1a = p.g1[tid * 2], g1b = p.g1[tid * 2 + 1];
  const float be1a = p.be1[tid * 2], be1b = p.be1[tid * 2 + 1];

  // resident weight fragments (bf16, MFMA B-operand order) — need launch_bounds(512,2)
  // so the 256-VGPR budget holds them without scratch spill (R1 lesson: cap 128 => 30ms)
  bf16x8 w0r[18], w1r[32];
  {
    const u16* q0 = p.wp0 + (size_t)(((ug * 4 + nt) * 36 + kh * 18) * 64 + lane) * 8;
#pragma unroll
    for (int s = 0; s < 18; ++s)
      w0r[s] = __builtin_bit_cast(bf16x8, *(const uint4*)(q0 + (size_t)s * 512));
    const u16* q1 = p.wp1 + (size_t)(((ug * 4 + nt) * 64 + kh * 32) * 64 + lane) * 8;
#pragma unroll
    for (int s = 0; s < 32; ++s)
      w1r[s] = __builtin_bit_cast(bf16x8, *(const uint4*)(q1 + (size_t)s * 512));
  }

  u32* ctr = p.bar + bg * 32;
  u32* gen = p.bar + 512 + bg * 32;

  float c0 = 0.f, c1 = 0.f;                     // cell state, tid<256: (row=tid>>4, unit=tid&15)
  const int gr = tid >> 4, gu = tid & 15;
  const int srow = tid >> 5, ssub = tid & 31;   // staging map
  const int am = lane & 15, aq = (lane >> 4) << 3;  // A-frag: row=lane&15, k += (lane>>4)*8

  __syncthreads();

  for (int t = 0; t < T_LEN; ++t) {
    const int cur = t & 1, rd = cur ^ 1;

    // ======== stage h0(t-1) rows into buf0 ========
    {
      const u16* hr = p.h0 + (size_t)(rd * 64 + bg * 16 + srow) * UNITS + ssub * 8;
      uint4 v0 = *(const uint4*)(hr);
      uint4 v1 = *(const uint4*)(hr + 256);
      uint4 v2 = *(const uint4*)(hr + 512);
      uint4 v3 = *(const uint4*)(hr + 768);
      *(uint4*)&buf0[srow][ssub * 8]       = v0;
      *(uint4*)&buf0[srow][256 + ssub * 8] = v1;
      *(uint4*)&buf0[srow][512 + ssub * 8] = v2;
      *(uint4*)&buf0[srow][768 + ssub * 8] = v3;
    }
    __syncthreads();

    // ======== L0 MFMA: z0 = [x | h0] @ Wp0 (x frags direct from global) ========
    f32x4 acc0 = {0.f, 0.f, 0.f, 0.f};
    if (kh == 0) {
      const u16* xr = p.xbf + (size_t)(t * 64 + bg * 16 + am) * FIN + aq;
#pragma unroll
      for (int s = 0; s < 4; ++s) {            // k in [0,128): x
        bf16x8 a = __builtin_bit_cast(bf16x8, *(const uint4*)(xr + s * 32));
        acc0 = __builtin_amdgcn_mfma_f32_16x16x32_bf16(a, w0r[s], acc0, 0, 0, 0);
      }
#pragma unroll
      for (int s = 4; s < 18; ++s) {           // k in [128,576): h0[0..448)
        bf16x8 a = __builtin_bit_cast(bf16x8, *(const uint4*)&buf0[am][s * 32 + aq - 128]);
        acc0 = __builtin_amdgcn_mfma_f32_16x16x32_bf16(a, w0r[s], acc0, 0, 0, 0);
      }
    } else {
#pragma unroll
      for (int s = 0; s < 18; ++s) {           // k in [576,1152): h0[448..1024)
        bf16x8 a = __builtin_bit_cast(bf16x8, *(const uint4*)&buf0[am][448 + s * 32 + aq]);
        acc0 = __builtin_amdgcn_mfma_f32_16x16x32_bf16(a, w0r[s], acc0, 0, 0, 0);
      }
    }
#pragma unroll
    for (int i = 0; i < 4; ++i)
      zb[kh][(lane >> 4) * 4 + i][nt * 16 + (lane & 15)] = acc0[i];
    __syncthreads();

    // ======== gates layer0 ========
    if (tid < 256) {
      const float* zr0 = &zb[0][gr][gu * 4];
      const float* zr1 = &zb[1][gr][gu * 4];
      float zi = zr0[0] + zr1[0] + b0s[gu * 4 + 0];
      float zf = zr0[1] + zr1[1] + b0s[gu * 4 + 1];
      float zg = zr0[2] + zr1[2] + b0s[gu * 4 + 2];
      float zo = zr0[3] + zr1[3] + b0s[gu * 4 + 3];
      float gi = sigm(zi), gf = sigm(zf), gg = tanhft(zg), go = sigm(zo);
      c0 = gf * c0 + gi * gg;
      float h = go * tanhft(c0);
      p.h0[(size_t)(cur * 64 + bg * 16 + gr) * UNITS + ug * 16 + gu] = f2bf(h);
    }
    bg_barrier(ctr, gen);  // ---- A: h0(t) visible within batch-group ----

    // ======== stats(h0) -> normpack o0 into buf0 ========
    {
      const u16* h0r = p.h0 + (size_t)(cur * 64 + bg * 16 + srow) * UNITS + ssub * 8;
      uint4 a0 = *(const uint4*)(h0r);
      uint4 a1 = *(const uint4*)(h0r + 256);
      uint4 a2 = *(const uint4*)(h0r + 512);
      uint4 a3 = *(const uint4*)(h0r + 768);

      float s1 = 0.f, s2 = 0.f;
      accst(a0, s1, s2); accst(a1, s1, s2); accst(a2, s1, s2); accst(a3, s1, s2);
#pragma unroll
      for (int m = 1; m <= 16; m <<= 1) { s1 += __shfl_xor(s1, m); s2 += __shfl_xor(s2, m); }
      if (ssub == 0) {
        float mu = s1 * (1.0f / 1024.0f);
        float va = s2 * (1.0f / 1024.0f) - mu * mu;
        mu_s[srow] = mu;
        sg_s[srow] = rsqrtf(va + 1e-3f);
      }
      __syncthreads();
      float mu = mu_s[srow], rs = sg_s[srow];
      *(uint4*)&buf0[srow][ssub * 8]       = normpack(a0, mu, rs, &g0s[ssub * 8], &be0s[ssub * 8]);
      *(uint4*)&buf0[srow][256 + ssub * 8] = normpack(a1, mu, rs, &g0s[256 + ssub * 8], &be0s[256 + ssub * 8]);
      *(uint4*)&buf0[srow][512 + ssub * 8] = normpack(a2, mu, rs, &g0s[512 + ssub * 8], &be0s[512 + ssub * 8]);
      *(uint4*)&buf0[srow][768 + ssub * 8] = normpack(a3, mu, rs, &g0s[768 + ssub * 8], &be0s[768 + ssub * 8]);
    }
    __syncthreads();

    // ======== L1 MFMA (single phase, all 8 waves): kh0=o0 from LDS, kh1=h1 from global ====
    f32x4 acc1 = {0.f, 0.f, 0.f, 0.f};
    if (kh == 0) {
#pragma unroll
      for (int s = 0; s < 32; ++s) {
        bf16x8 a = __builtin_bit_cast(bf16x8, *(const uint4*)&buf0[am][s * 32 + aq]);
        acc1 = __builtin_amdgcn_mfma_f32_16x16x32_bf16(a, w1r[s], acc1, 0, 0, 0);
      }
    } else {
      const u16* hb = p.h1 + (size_t)(rd * 64 + bg * 16 + am) * UNITS + aq;
#pragma unroll
      for (int s = 0; s < 32; ++s) {
        bf16x8 a = __builtin_bit_cast(bf16x8, *(const uint4*)(hb + s * 32));
        acc1 = __builtin_amdgcn_mfma_f32_16x16x32_bf16(a, w1r[s], acc1, 0, 0, 0);
      }
    }
#pragma unroll
    for (int i = 0; i < 4; ++i)
      zb[kh][(lane >> 4) * 4 + i][nt * 16 + (lane & 15)] = acc1[i];
    __syncthreads();

    // ======== gates layer1 ========
    if (tid < 256) {
      const float* zr0 = &zb[0][gr][gu * 4];
      const float* zr1 = &zb[1][gr][gu * 4];
      float zi = zr0[0] + zr1[0] + b1s[gu * 4 + 0];
      float zf = zr0[1] + zr1[1] + b1s[gu * 4 + 1];
      float zg = zr0[2] + zr1[2] + b1s[gu * 4 + 2];
      float zo = zr0[3] + zr1[3] + b1s[gu * 4 + 3];
      float gi = sigm(zi), gf = sigm(zf), gg = tanhft(zg), go = sigm(zo);
      c1 = gf * c1 + gi * gg;
      float h = go * tanhft(c1);
      p.h1[(size_t)(cur * 64 + bg * 16 + gr) * UNITS + ug * 16 + gu] = f2bf(h);
    }
    bg_barrier(ctr, gen);  // ---- B: h1(t) visible ----

    // ======== FC + softmax (one block per batch row) ========
    if (ug < 16) {
      const int row = bg * 16 + ug;
      const u16* hr = p.h1 + (size_t)(cur * 64 + row) * UNITS;
      u32 hv = *(const u32*)(hr + tid * 2);
      float f0 = bf2f((u16)(hv & 0xffffu)), f1 = bf2f((u16)(hv >> 16));
      float s1 = f0 + f1, s2 = f0 * f0 + f1 * f1;
#pragma unroll
      for (int m = 1; m <= 32; m <<= 1) { s1 += __shfl_xor(s1, m); s2 += __shfl_xor(s2, m); }
      if (lane == 0) { red[wv][0] = s1; red[wv][1] = s2; }
      __syncthreads();
      if (tid == 0) {
        float t1 = 0.f, t2 = 0.f;
#pragma unroll
        for (int w2 = 0; w2 < 8; ++w2) { t1 += red[w2][0]; t2 += red[w2][1]; }
        float mu = t1 * (1.0f / 1024.0f);
        float va = t2 * (1.0f / 1024.0f) - mu * mu;
        mu_s[0] = mu;
        sg_s[0] = rsqrtf(va + 1e-3f);
      }
      __syncthreads();
      {
        float mu = mu_s[0], rs = sg_s[0];
        float* o1f = (float*)&buf0[0][0];
        o1f[tid * 2]     = (f0 - mu) * rs * g1a + be1a;
        o1f[tid * 2 + 1] = (f1 - mu) * rs * g1b + be1b;
      }
      __syncthreads();
      if (tid < 256) {
        const int cls = tid & 15, ks = tid >> 4;
        const float* o1f = (const float*)&buf0[0][0];
        const u16* wrow = p.wfc + cls * 1024 + ks * 64;
        float pa = 0.f;
#pragma unroll
        for (int q8 = 0; q8 < 8; ++q8) {
          uint4 wv4 = *(const uint4*)(wrow + q8 * 8);
          u32 aa[4] = {wv4.x, wv4.y, wv4.z, wv4.w};
#pragma unroll
          for (int e = 0; e < 4; ++e) {
            int k = ks * 64 + q8 * 8 + e * 2;
            pa += o1f[k]     * bf2f((u16)(aa[e] & 0xffffu));
            pa += o1f[k + 1] * bf2f((u16)(aa[e] >> 16));
          }
        }
        zb[0][ks][cls] = pa;
      }
      __syncthreads();
      if (tid < 16) {
        float lg = p.bfc[tid];
#pragma unroll
        for (int ks = 0; ks < 16; ++ks) lg += zb[0][ks][tid];
        lbuf[tid] = lg;
      }
      __syncthreads();
      if (tid < 16) {
        float mx = lbuf[0];
#pragma unroll
        for (int j2 = 1; j2 < 16; ++j2) mx = fmaxf(mx, lbuf[j2]);
        float ssum = 0.f;
#pragma unroll
        for (int j2 = 0; j2 < 16; ++j2) ssum += __expf(lbuf[j2] - mx);
        p.out[((size_t)row * T_LEN + t) * 16 + tid] = __expf(lbuf[tid] - mx) / ssum;
      }
    }
  }
}

extern "C" void kernel_launch(void* const* d_in, const int* in_sizes, int n_in,
                              void* d_out, int out_size, void* d_ws, size_t ws_size,
                              hipStream_t stream) {
  (void)in_sizes; (void)n_in; (void)out_size;
  if (ws_size < (size_t)WS_NEED) return;

  const float* inp = (const float*)d_in[0];
  const float* W0  = (const float*)d_in[1];
  const float* U0  = (const float*)d_in[2];
  const float* b0  = (const float*)d_in[3];
  const float* g0  = (const float*)d_in[4];
  const float* be0 = (const float*)d_in[5];
  const float* W1  = (const float*)d_in[6];
  const float* U1  = (const float*)d_in[7];
  const float* b1  = (const float*)d_in[8];
  const float* g1  = (const float*)d_in[9];
  const float* be1 = (const float*)d_in[10];
  const float* Wfc = (const float*)d_in[11];
  const float* bfc = (const float*)d_in[12];

  char* ws = (char*)d_ws;
  u32* bar  = (u32*)(ws + O_BAR);
  u16* xbf  = (u16*)(ws + O_XBF);
  u16* wp0  = (u16*)(ws + O_WP0);
  u16* wp1  = (u16*)(ws + O_WP1);
  u16* wfcT = (u16*)(ws + O_WFC);
  u16* h0   = (u16*)(ws + O_H0);
  u16* h1   = (u16*)(ws + O_H1);

  k_zero<<<4, 256, 0, stream>>>(bar, 1024);
  k_zero<<<512, 256, 0, stream>>>((u32*)(ws + O_H0), 131072);  // h0+h1 (contiguous)
  k_pack_x<<<16384, 256, 0, stream>>>(inp, xbf);
  k_pack_w0<<<18432, 256, 0, stream>>>(W0, U0, wp0);
  k_pack_w1<<<32768, 256, 0, stream>>>(W1, U1, wp1);
  k_pack_wfc<<<64, 256, 0, stream>>>(Wfc, wfcT);

  KP p;
  p.xbf = xbf; p.wp0 = wp0; p.wp1 = wp1; p.wfc = wfcT;
  p.h0 = h0; p.h1 = h1; p.bar = bar;
  p.b0 = b0; p.g0 = g0; p.be0 = be0;
  p.b1 = b1; p.g1 = g1; p.be1 = be1;
  p.bfc = bfc; p.out = (float*)d_out;

  void* args[] = { &p };
  hipLaunchCooperativeKernel((const void*)k_persist, dim3(256), dim3(512), args, 0, stream);
}

// Round 3
// 7682.961 us; speedup vs baseline: 3.7861x; 3.7782x over previous
//
#include <hip/hip_runtime.h>

typedef unsigned short u16;
typedef unsigned int u32;
typedef unsigned long long u64;
typedef __bf16 bf16x8 __attribute__((ext_vector_type(8)));
typedef float f32x4 __attribute__((ext_vector_type(4)));

#define T_LEN 512
#define BATCH 64
#define FIN 128
#define UNITS 1024

// ---- workspace layout (bytes) ----
#define O_BAR   0
#define SZ_BAR  8192
#define O_XBF   SZ_BAR
#define SZ_XBF  (T_LEN*BATCH*FIN*2)
#define O_WP0   (O_XBF + SZ_XBF)
#define SZ_WP0  (1152*4096*2)
#define O_WP1   (O_WP0 + SZ_WP0)
#define SZ_WP1  (2048*4096*2)
#define O_WFC   (O_WP1 + SZ_WP1)
#define SZ_WFC  (16*1024*2)
#define O_H0    (O_WFC + SZ_WFC)
#define SZ_H    (BATCH*UNITS*2)
#define O_H1    (O_H0 + SZ_H)
#define WS_NEED (O_H1 + SZ_H)

__device__ __forceinline__ float bf2f(u16 s) {
  u32 u = ((u32)s) << 16;
  return __builtin_bit_cast(float, u);
}
__device__ __forceinline__ u16 f2bf(float f) {
  u32 u = __builtin_bit_cast(u32, f);
  u32 r = (u + 0x7FFFu + ((u >> 16) & 1u)) >> 16;
  return (u16)r;
}
__device__ __forceinline__ float sigm(float x) { return 1.0f / (1.0f + __expf(-x)); }
__device__ __forceinline__ float tanhft(float x) { return 1.0f - 2.0f / (__expf(2.0f * x) + 1.0f); }

// coherent (LLC, bypass stale L1/L2) 16B load as 2x relaxed agent u64 atomics — no buffer_inv
__device__ __forceinline__ uint4 ldh16(const u16* q) {
  u64 a = __hip_atomic_load((const u64*)q,     __ATOMIC_RELAXED, __HIP_MEMORY_SCOPE_AGENT);
  u64 b = __hip_atomic_load((const u64*)q + 1, __ATOMIC_RELAXED, __HIP_MEMORY_SCOPE_AGENT);
  uint4 r; r.x = (u32)a; r.y = (u32)(a >> 32); r.z = (u32)b; r.w = (u32)(b >> 32);
  return r;
}
__device__ __forceinline__ void sth(u16* q, u16 v) {
  __hip_atomic_store(q, v, __ATOMIC_RELAXED, __HIP_MEMORY_SCOPE_AGENT);
}

// ---------------- prep kernels ----------------
__global__ void k_zero(u32* p, int n) {
  int i = blockIdx.x * 256 + threadIdx.x;
  if (i < n) p[i] = 0u;
}

__global__ void k_pack_x(const float* __restrict__ src, u16* __restrict__ dst) {
  int i = blockIdx.x * 256 + threadIdx.x;      // < 512*64*128
  int f = i & 127, tb = i >> 7;
  int b = tb & 63, t = tb >> 6;
  dst[i] = f2bf(src[(b * T_LEN + t) * FIN + f]);
}

// Wp0: [ug][nt][ktg(36)][lane][8] over K=[W0(128);U0(1024)], cols unit-gate interleaved
__global__ void k_pack_w0(const float* __restrict__ W0, const float* __restrict__ U0,
                          u16* __restrict__ dst) {
  int i = blockIdx.x * 256 + threadIdx.x;      // < 4096*1152
  int j = i & 7, lane = (i >> 3) & 63, rest = i >> 9;
  int ktg = rest % 36, tmp = rest / 36;
  int nt = tmp & 3, ug = tmp >> 2;
  int k = ktg * 32 + ((lane >> 4) << 3) + j;
  int rr = nt * 16 + (lane & 15);
  int gate = rr & 3, ul = rr >> 2;
  int col = gate * 1024 + ug * 16 + ul;
  float v = (k < FIN) ? W0[k * 4096 + col] : U0[(k - FIN) * 4096 + col];
  dst[i] = f2bf(v);
}

// Wp1: [ug][nt][ktg(64)][lane][8] over K=[W1(1024);U1(1024)]
__global__ void k_pack_w1(const float* __restrict__ W1, const float* __restrict__ U1,
                          u16* __restrict__ dst) {
  int i = blockIdx.x * 256 + threadIdx.x;      // < 4096*2048
  int j = i & 7, lane = (i >> 3) & 63, rest = i >> 9;
  int ktg = rest & 63, tmp = rest >> 6;
  int nt = tmp & 3, ug = tmp >> 2;
  int k = ktg * 32 + ((lane >> 4) << 3) + j;
  int rr = nt * 16 + (lane & 15);
  int gate = rr & 3, ul = rr >> 2;
  int col = gate * 1024 + ug * 16 + ul;
  float v = (k < UNITS) ? W1[k * 4096 + col] : U1[(k - UNITS) * 4096 + col];
  dst[i] = f2bf(v);
}

__global__ void k_pack_wfc(const float* __restrict__ Wfc, u16* __restrict__ dst) {
  int i = blockIdx.x * 256 + threadIdx.x;      // < 16*1024
  int k = i & 1023, c = i >> 10;
  dst[c * 1024 + k] = f2bf(Wfc[k * 16 + c]);
}

// ---------------- persistent kernel ----------------
struct KP {
  const u16* xbf; const u16* wp0; const u16* wp1; const u16* wfc;
  u16* h0; u16* h1; u32* bar;
  const float* b0; const float* g0; const float* be0;
  const float* b1; const float* g1; const float* be1;
  const float* bfc; float* out;
};

__device__ __forceinline__ void accst(uint4 v, float& s1, float& s2) {
  u32 a[4] = {v.x, v.y, v.z, v.w};
#pragma unroll
  for (int e = 0; e < 4; ++e) {
    float f0 = bf2f((u16)(a[e] & 0xffffu));
    float f1 = bf2f((u16)(a[e] >> 16));
    s1 += f0 + f1;
    s2 += f0 * f0 + f1 * f1;
  }
}

__device__ __forceinline__ uint4 normpack(uint4 v, float mu, float rs,
                                          const float* gg, const float* bb) {
  u32 a[4] = {v.x, v.y, v.z, v.w};
  u32 o[4];
#pragma unroll
  for (int e = 0; e < 4; ++e) {
    float f0 = (bf2f((u16)(a[e] & 0xffffu)) - mu) * rs * gg[2 * e] + bb[2 * e];
    float f1 = (bf2f((u16)(a[e] >> 16)) - mu) * rs * gg[2 * e + 1] + bb[2 * e + 1];
    o[e] = (u32)f2bf(f0) | ((u32)f2bf(f1) << 16);
  }
  uint4 r; r.x = o[0]; r.y = o[1]; r.z = o[2]; r.w = o[3];
  return r;
}

// flag/ballot barrier over the 64 blocks of one batch-group. All atomics RELAXED
// agent-scope (sc0sc1 per-access coherent): no buffer_inv / buffer_wbl2 (the R2
// killer: acquire-poll invalidated the whole per-XCD L2 every iteration).
// __syncthreads() drains vmcnt(0) => prior coherent h-stores are LLC-visible
// before the flag store issues.
__device__ __forceinline__ void barrier_bg(u32* gen, u32* flags, int ug, int lane,
                                           int wv, u32 ep) {
  __syncthreads();
  if (wv == 0) {
    if (lane == 0)
      __hip_atomic_store(flags + ug * 4, ep, __ATOMIC_RELAXED, __HIP_MEMORY_SCOPE_AGENT);
    if (ug == 0) {
      for (;;) {
        u32 v = __hip_atomic_load(flags + lane * 4, __ATOMIC_RELAXED, __HIP_MEMORY_SCOPE_AGENT);
        if (__ballot(v >= ep) == ~0ull) break;
        __builtin_amdgcn_s_sleep(1);
      }
      if (lane == 0)
        __hip_atomic_store(gen, ep, __ATOMIC_RELAXED, __HIP_MEMORY_SCOPE_AGENT);
    } else if (lane == 0) {
      while (__hip_atomic_load(gen, __ATOMIC_RELAXED, __HIP_MEMORY_SCOPE_AGENT) < ep)
        __builtin_amdgcn_s_sleep(1);
    }
  }
  __syncthreads();
  asm volatile("" ::: "memory");
}

__global__ void __launch_bounds__(512, 2) k_persist(KP p) {
  const int tid = threadIdx.x;
  const int ug = blockIdx.x & 63, bg = blockIdx.x >> 6;
  const int lane = tid & 63, wv = tid >> 6;
  const int nt = wv & 3, kh = wv >> 2;

  __shared__ __align__(16) u16 bufA[16][1032];  // raw h0(t-1), carried across steps
  __shared__ __align__(16) u16 bufB[16][1032];  // raw h1(t-1), carried across steps
  __shared__ __align__(16) u16 buf0[16][1032];  // o0(t) staging; FC float scratch (aliased)
  __shared__ float zb[2][16][68];               // kh-partial z tiles
  __shared__ float g0s[1024], be0s[1024];
  __shared__ float b0s[64], b1s[64];
  __shared__ float mu_s[16], sg_s[16];
  __shared__ float lbuf[16];

  for (int i = tid; i < 1024; i += 512) { g0s[i] = p.g0[i]; be0s[i] = p.be0[i]; }
  if (tid < 64) {
    int gate = tid & 3, ul = tid >> 2;
    b0s[tid] = p.b0[gate * 1024 + ug * 16 + ul];
    b1s[tid] = p.b1[gate * 1024 + ug * 16 + ul];
  }
  // zero the carried h buffers (t=0 state)
  {
    u32* za = (u32*)&bufA[0][0];
    u32* zc = (u32*)&bufB[0][0];
    for (int i = tid; i < 16 * 1032 / 2; i += 512) { za[i] = 0u; zc[i] = 0u; }
  }
  const float g1a = p.g1[tid * 2], g1b = p.g1[tid * 2 + 1];
  const float be1a = p.be1[tid * 2], be1b = p.be1[tid * 2 + 1];

  // resident weight fragments (bf16, MFMA B-operand order); ~200 regs live in
  // the unified VGPR/AGPR file (R2: occupancy 2 waves/EU => total alloc <=256, no spill)
  bf16x8 w0r[18], w1r[32];
  {
    const u16* q0 = p.wp0 + (size_t)(((ug * 4 + nt) * 36 + kh * 18) * 64 + lane) * 8;
#pragma unroll
    for (int s = 0; s < 18; ++s)
      w0r[s] = __builtin_bit_cast(bf16x8, *(const uint4*)(q0 + (size_t)s * 512));
    const u16* q1 = p.wp1 + (size_t)(((ug * 4 + nt) * 64 + kh * 32) * 64 + lane) * 8;
#pragma unroll
    for (int s = 0; s < 32; ++s)
      w1r[s] = __builtin_bit_cast(bf16x8, *(const uint4*)(q1 + (size_t)s * 512));
  }

  u32* gen   = p.bar + bg * 64;                 // 256B-spaced gen words
  u32* flags = p.bar + 256 + bg * 256;          // 64 flags * 16B spacing per bg

  float c0 = 0.f, c1 = 0.f;                     // cell state, tid<256: (row=tid>>4, unit=tid&15)
  const int gr = tid >> 4, gu = tid & 15;
  const int srow = tid >> 5, ssub = tid & 31;   // row-staging map (32 thr/row)
  const int am = lane & 15, aq = (lane >> 4) << 3;  // A-frag: row=lane&15, k += (lane>>4)*8

  __syncthreads();

  for (int t = 0; t < T_LEN; ++t) {
    const u32 epA = 2 * t + 1, epB = 2 * t + 2;

    // ======== L0 MFMA: z0 = [x | h0(t-1)] @ Wp0 (x global-cached, h0 from bufA) ========
    f32x4 acc0 = {0.f, 0.f, 0.f, 0.f};
    if (kh == 0) {
      const u16* xr = p.xbf + (size_t)(t * 64 + bg * 16 + am) * FIN + aq;
#pragma unroll
      for (int s = 0; s < 4; ++s) {            // k in [0,128): x
        bf16x8 a = __builtin_bit_cast(bf16x8, *(const uint4*)(xr + s * 32));
        acc0 = __builtin_amdgcn_mfma_f32_16x16x32_bf16(a, w0r[s], acc0, 0, 0, 0);
      }
#pragma unroll
      for (int s = 4; s < 18; ++s) {           // k in [128,576): h0[0..448)
        bf16x8 a = __builtin_bit_cast(bf16x8, *(const uint4*)&bufA[am][s * 32 + aq - 128]);
        acc0 = __builtin_amdgcn_mfma_f32_16x16x32_bf16(a, w0r[s], acc0, 0, 0, 0);
      }
    } else {
#pragma unroll
      for (int s = 0; s < 18; ++s) {           // k in [576,1152): h0[448..1024)
        bf16x8 a = __builtin_bit_cast(bf16x8, *(const uint4*)&bufA[am][448 + s * 32 + aq]);
        acc0 = __builtin_amdgcn_mfma_f32_16x16x32_bf16(a, w0r[s], acc0, 0, 0, 0);
      }
    }
#pragma unroll
    for (int i = 0; i < 4; ++i)
      zb[kh][(lane >> 4) * 4 + i][nt * 16 + (lane & 15)] = acc0[i];
    __syncthreads();

    // ======== gates layer0 -> coherent store of this block's 16 units ========
    if (tid < 256) {
      const float* zr0 = &zb[0][gr][gu * 4];
      const float* zr1 = &zb[1][gr][gu * 4];
      float zi = zr0[0] + zr1[0] + b0s[gu * 4 + 0];
      float zf = zr0[1] + zr1[1] + b0s[gu * 4 + 1];
      float zg = zr0[2] + zr1[2] + b0s[gu * 4 + 2];
      float zo = zr0[3] + zr1[3] + b0s[gu * 4 + 3];
      float gi = sigm(zi), gf = sigm(zf), gg = tanhft(zg), go = sigm(zo);
      c0 = gf * c0 + gi * gg;
      float h = go * tanhft(c0);
      sth(p.h0 + (size_t)(bg * 16 + gr) * UNITS + ug * 16 + gu, f2bf(h));
    }
    barrier_bg(gen, flags, ug, lane, wv, epA);   // ---- A: h0(t) visible ----

    // ======== load h0(t) rows, stats, raw->bufA (next step), norm->buf0 ========
    {
      const u16* h0r = p.h0 + (size_t)(bg * 16 + srow) * UNITS + ssub * 8;
      uint4 a0 = ldh16(h0r);
      uint4 a1 = ldh16(h0r + 256);
      uint4 a2 = ldh16(h0r + 512);
      uint4 a3 = ldh16(h0r + 768);

      float s1 = 0.f, s2 = 0.f;
      accst(a0, s1, s2); accst(a1, s1, s2); accst(a2, s1, s2); accst(a3, s1, s2);
#pragma unroll
      for (int m = 1; m <= 16; m <<= 1) { s1 += __shfl_xor(s1, m); s2 += __shfl_xor(s2, m); }
      if (ssub == 0) {
        float mu = s1 * (1.0f / 1024.0f);
        float va = s2 * (1.0f / 1024.0f) - mu * mu;
        mu_s[srow] = mu;
        sg_s[srow] = rsqrtf(va + 1e-3f);
      }
      *(uint4*)&bufA[srow][ssub * 8]       = a0;
      *(uint4*)&bufA[srow][256 + ssub * 8] = a1;
      *(uint4*)&bufA[srow][512 + ssub * 8] = a2;
      *(uint4*)&bufA[srow][768 + ssub * 8] = a3;
      __syncthreads();
      float mu = mu_s[srow], rs = sg_s[srow];
      *(uint4*)&buf0[srow][ssub * 8]       = normpack(a0, mu, rs, &g0s[ssub * 8], &be0s[ssub * 8]);
      *(uint4*)&buf0[srow][256 + ssub * 8] = normpack(a1, mu, rs, &g0s[256 + ssub * 8], &be0s[256 + ssub * 8]);
      *(uint4*)&buf0[srow][512 + ssub * 8] = normpack(a2, mu, rs, &g0s[512 + ssub * 8], &be0s[512 + ssub * 8]);
      *(uint4*)&buf0[srow][768 + ssub * 8] = normpack(a3, mu, rs, &g0s[768 + ssub * 8], &be0s[768 + ssub * 8]);
    }
    __syncthreads();

    // ======== L1 MFMA: A = [o0(t) | h1(t-1)], kh0 from buf0, kh1 from bufB ========
    f32x4 acc1 = {0.f, 0.f, 0.f, 0.f};
    if (kh == 0) {
#pragma unroll
      for (int s = 0; s < 32; ++s) {
        bf16x8 a = __builtin_bit_cast(bf16x8, *(const uint4*)&buf0[am][s * 32 + aq]);
        acc1 = __builtin_amdgcn_mfma_f32_16x16x32_bf16(a, w1r[s], acc1, 0, 0, 0);
      }
    } else {
#pragma unroll
      for (int s = 0; s < 32; ++s) {
        bf16x8 a = __builtin_bit_cast(bf16x8, *(const uint4*)&bufB[am][s * 32 + aq]);
        acc1 = __builtin_amdgcn_mfma_f32_16x16x32_bf16(a, w1r[s], acc1, 0, 0, 0);
      }
    }
#pragma unroll
    for (int i = 0; i < 4; ++i)
      zb[kh][(lane >> 4) * 4 + i][nt * 16 + (lane & 15)] = acc1[i];
    __syncthreads();

    // ======== gates layer1 -> coherent store ========
    if (tid < 256) {
      const float* zr0 = &zb[0][gr][gu * 4];
      const float* zr1 = &zb[1][gr][gu * 4];
      float zi = zr0[0] + zr1[0] + b1s[gu * 4 + 0];
      float zf = zr0[1] + zr1[1] + b1s[gu * 4 + 1];
      float zg = zr0[2] + zr1[2] + b1s[gu * 4 + 2];
      float zo = zr0[3] + zr1[3] + b1s[gu * 4 + 3];
      float gi = sigm(zi), gf = sigm(zf), gg = tanhft(zg), go = sigm(zo);
      c1 = gf * c1 + gi * gg;
      float h = go * tanhft(c1);
      sth(p.h1 + (size_t)(bg * 16 + gr) * UNITS + ug * 16 + gu, f2bf(h));
    }
    barrier_bg(gen, flags, ug, lane, wv, epB);   // ---- B: h1(t) visible ----

    // ======== load h1(t) rows, stats, raw->bufB (next step) ========
    {
      const u16* h1r = p.h1 + (size_t)(bg * 16 + srow) * UNITS + ssub * 8;
      uint4 a0 = ldh16(h1r);
      uint4 a1 = ldh16(h1r + 256);
      uint4 a2 = ldh16(h1r + 512);
      uint4 a3 = ldh16(h1r + 768);
      float s1 = 0.f, s2 = 0.f;
      accst(a0, s1, s2); accst(a1, s1, s2); accst(a2, s1, s2); accst(a3, s1, s2);
#pragma unroll
      for (int m = 1; m <= 16; m <<= 1) { s1 += __shfl_xor(s1, m); s2 += __shfl_xor(s2, m); }
      if (ssub == 0) {
        float mu = s1 * (1.0f / 1024.0f);
        float va = s2 * (1.0f / 1024.0f) - mu * mu;
        mu_s[srow] = mu;
        sg_s[srow] = rsqrtf(va + 1e-3f);
      }
      *(uint4*)&bufB[srow][ssub * 8]       = a0;
      *(uint4*)&bufB[srow][256 + ssub * 8] = a1;
      *(uint4*)&bufB[srow][512 + ssub * 8] = a2;
      *(uint4*)&bufB[srow][768 + ssub * 8] = a3;
    }
    __syncthreads();

    // ======== FC + softmax (blocks ug<16 only; row = bg*16+ug, h1 from bufB) ========
    if (ug < 16) {
      const int row = bg * 16 + ug;
      u32 hv = *(const u32*)&bufB[ug][tid * 2];
      float f0 = bf2f((u16)(hv & 0xffffu)), f1 = bf2f((u16)(hv >> 16));
      {
        float mu = mu_s[ug], rs = sg_s[ug];
        float* o1f = (float*)&buf0[0][0];
        o1f[tid * 2]     = (f0 - mu) * rs * g1a + be1a;
        o1f[tid * 2 + 1] = (f1 - mu) * rs * g1b + be1b;
      }
      __syncthreads();
      if (tid < 256) {
        const int cls = tid & 15, ks = tid >> 4;
        const float* o1f = (const float*)&buf0[0][0];
        const u16* wrow = p.wfc + cls * 1024 + ks * 64;
        float pa = 0.f;
#pragma unroll
        for (int q8 = 0; q8 < 8; ++q8) {
          uint4 wv4 = *(const uint4*)(wrow + q8 * 8);
          u32 aa[4] = {wv4.x, wv4.y, wv4.z, wv4.w};
#pragma unroll
          for (int e = 0; e < 4; ++e) {
            int k = ks * 64 + q8 * 8 + e * 2;
            pa += o1f[k]     * bf2f((u16)(aa[e] & 0xffffu));
            pa += o1f[k + 1] * bf2f((u16)(aa[e] >> 16));
          }
        }
        zb[0][ks][cls] = pa;
      }
      __syncthreads();
      if (tid < 16) {
        float lg = p.bfc[tid];
#pragma unroll
        for (int ks = 0; ks < 16; ++ks) lg += zb[0][ks][tid];
        lbuf[tid] = lg;
      }
      __syncthreads();
      if (tid < 16) {
        float mx = lbuf[0];
#pragma unroll
        for (int j2 = 1; j2 < 16; ++j2) mx = fmaxf(mx, lbuf[j2]);
        float ssum = 0.f;
#pragma unroll
        for (int j2 = 0; j2 < 16; ++j2) ssum += __expf(lbuf[j2] - mx);
        p.out[((size_t)row * T_LEN + t) * 16 + tid] = __expf(lbuf[tid] - mx) / ssum;
      }
      __syncthreads();  // protect zb/buf0 scratch against next step's writes
    }
  }
}

extern "C" void kernel_launch(void* const* d_in, const int* in_sizes, int n_in,
                              void* d_out, int out_size, void* d_ws, size_t ws_size,
                              hipStream_t stream) {
  (void)in_sizes; (void)n_in; (void)out_size;
  if (ws_size < (size_t)WS_NEED) return;

  const float* inp = (const float*)d_in[0];
  const float* W0  = (const float*)d_in[1];
  const float* U0  = (const float*)d_in[2];
  const float* b0  = (const float*)d_in[3];
  const float* g0  = (const float*)d_in[4];
  const float* be0 = (const float*)d_in[5];
  const float* W1  = (const float*)d_in[6];
  const float* U1  = (const float*)d_in[7];
  const float* b1  = (const float*)d_in[8];
  const float* g1  = (const float*)d_in[9];
  const float* be1 = (const float*)d_in[10];
  const float* Wfc = (const float*)d_in[11];
  const float* bfc = (const float*)d_in[12];

  char* ws = (char*)d_ws;
  u32* bar  = (u32*)(ws + O_BAR);
  u16* xbf  = (u16*)(ws + O_XBF);
  u16* wp0  = (u16*)(ws + O_WP0);
  u16* wp1  = (u16*)(ws + O_WP1);
  u16* wfcT = (u16*)(ws + O_WFC);
  u16* h0   = (u16*)(ws + O_H0);
  u16* h1   = (u16*)(ws + O_H1);

  k_zero<<<8, 256, 0, stream>>>(bar, 2048);
  k_pack_x<<<16384, 256, 0, stream>>>(inp, xbf);
  k_pack_w0<<<18432, 256, 0, stream>>>(W0, U0, wp0);
  k_pack_w1<<<32768, 256, 0, stream>>>(W1, U1, wp1);
  k_pack_wfc<<<64, 256, 0, stream>>>(Wfc, wfcT);

  KP p;
  p.xbf = xbf; p.wp0 = wp0; p.wp1 = wp1; p.wfc = wfcT;
  p.h0 = h0; p.h1 = h1; p.bar = bar;
  p.b0 = b0; p.g0 = g0; p.be0 = be0;
  p.b1 = b1; p.g1 = g1; p.be1 = be1;
  p.bfc = bfc; p.out = (float*)d_out;

  void* args[] = { &p };
  hipLaunchCooperativeKernel((const void*)k_persist, dim3(256), dim3(512), args, 0, stream);
}